// Round 1
// baseline (118.702 us; speedup 1.0000x reference)
//
#include <hip/hip_runtime.h>
#include <math.h>

#define NN 8192
#define MM 4096
#define DD 128
#define TDIM 32
#define H1DIM 64
#define H2DIM 32
#define FEAT (3*DD + TDIM)   // 416
#define MAXK 256
#define BIGF 1e30f

// Pass 1: compress dense incidence H (N x M, row-major) into per-column index
// lists. Coalesced float4 read of H; atomic append of row index n per nonzero.
__global__ void build_csc(const float* __restrict__ H,
                          int* __restrict__ cnt, int* __restrict__ idxlist) {
    int tid = blockIdx.x * blockDim.x + threadIdx.x;   // one float4 per thread
    const float4* H4 = reinterpret_cast<const float4*>(H);
    float4 v = H4[tid];
    int base = tid * 4;              // flat index into H
    int n = base / MM;               // row (node)
    int m = base % MM;               // col (hyperedge); MM % 4 == 0 so all 4 same row
    float vals[4] = {v.x, v.y, v.z, v.w};
    #pragma unroll
    for (int i = 0; i < 4; ++i) {
        if (vals[i] != 0.0f) {
            int p = atomicAdd(&cnt[m + i], 1);
            if (p < MAXK) idxlist[(m + i) * MAXK + p] = n;
        }
    }
}

// Pass 2: per-hyperedge stats. Block = one hyperedge (M blocks), thread = dim d.
// Gathers x[n, d] for each member node (coalesced 512B per node across block).
__global__ void stats_kernel(const float* __restrict__ x,
                             const int* __restrict__ cnt,
                             const int* __restrict__ idxlist,
                             float* __restrict__ feat,
                             const float* __restrict__ tptr,
                             const float* __restrict__ Wt,
                             const float* __restrict__ bt) {
    int m = blockIdx.x;
    int d = threadIdx.x;
    int K = cnt[m]; if (K > MAXK) K = MAXK;
    const int* lst = idxlist + m * MAXK;
    float s = 0.f, s2 = 0.f, mx = -BIGF, mn = BIGF;
    for (int i = 0; i < K; ++i) {
        int n = lst[i];                  // wave-uniform (scalar load)
        float v = x[n * DD + d];         // coalesced across d
        s  += v;
        s2 += v * v;
        mx = fmaxf(mx, v);
        mn = fminf(mn, v);
    }
    float deg = (K > 0) ? (float)K : 1.0f;   // clip(sum H, 1.0)
    float mu  = s / deg;
    float var = s2 / deg - mu * mu;
    float sg  = sqrtf(fmaxf(var, 1e-8f));
    float dl  = (K > 0) ? (mx - mn) : 0.0f;
    float* f = feat + m * FEAT;
    f[d]        = mu;
    f[DD + d]   = sg;
    f[2*DD + d] = dl;
    if (d < TDIM) {
        float te = tptr[0] * Wt[d] + bt[d];  // W_t is (TDIM,1)
        f[3*DD + d] = fmaxf(te, 0.0f);
    }
}

// Pass 3: tiny MLP 416 -> 64 -> 32 -> 1 (sigmoid). 4 hyperedges per block.
// Wave layout: lanes of a wave all share the same feat row (broadcast reads);
// W1 rows stream per-lane (L1-resident: 64 active lines).
__global__ void mlp_kernel(const float* __restrict__ feat,
                           const float* __restrict__ W1, const float* __restrict__ b1,
                           const float* __restrict__ W2, const float* __restrict__ b2,
                           const float* __restrict__ W3, const float* __restrict__ b3,
                           float* __restrict__ out) {
    int t = threadIdx.x;
    int rbase = blockIdx.x * 4;
    int j  = t & 63;        // output unit of layer 1
    int rr = t >> 6;        // which of the 4 rows
    int row = rbase + rr;

    __shared__ float hs1[4][H1DIM];
    __shared__ float hs2[4][H2DIM];

    const float4* f4 = reinterpret_cast<const float4*>(feat + row * FEAT);
    const float4* w4 = reinterpret_cast<const float4*>(W1 + j * FEAT);
    float acc = b1[j];
    #pragma unroll 4
    for (int k = 0; k < FEAT / 4; ++k) {
        float4 a = f4[k];
        float4 b = w4[k];
        acc += a.x * b.x + a.y * b.y + a.z * b.z + a.w * b.w;
    }
    hs1[rr][j] = fmaxf(acc, 0.f);
    __syncthreads();

    if (t < 4 * H2DIM) {
        int r2 = t >> 5, j2 = t & 31;
        float a2 = b2[j2];
        const float* w2 = W2 + j2 * H1DIM;
        #pragma unroll
        for (int k = 0; k < H1DIM; ++k) a2 += hs1[r2][k] * w2[k];
        hs2[r2][j2] = fmaxf(a2, 0.f);
    }
    __syncthreads();

    if (t < 4) {
        float a3 = b3[0];
        #pragma unroll
        for (int k = 0; k < H2DIM; ++k) a3 += hs2[t][k] * W3[k];
        out[rbase + t] = 1.0f / (1.0f + expf(-a3));
    }
}

extern "C" void kernel_launch(void* const* d_in, const int* in_sizes, int n_in,
                              void* d_out, int out_size, void* d_ws, size_t ws_size,
                              hipStream_t stream) {
    const float* x   = (const float*)d_in[0];   // (N, D)
    const float* H   = (const float*)d_in[1];   // (N, M)
    const float* t   = (const float*)d_in[2];   // (1,)
    const float* Wt  = (const float*)d_in[3];   // (TDIM, 1)
    const float* bt  = (const float*)d_in[4];   // (TDIM,)
    const float* W1  = (const float*)d_in[5];   // (64, 416)
    const float* b1  = (const float*)d_in[6];
    const float* W2  = (const float*)d_in[7];   // (32, 64)
    const float* b2  = (const float*)d_in[8];
    const float* W3  = (const float*)d_in[9];   // (1, 32)
    const float* b3  = (const float*)d_in[10];
    float* out = (float*)d_out;

    // workspace layout
    int* cnt     = (int*)d_ws;                          // M ints
    int* idxlist = cnt + MM;                            // M * MAXK ints (4 MB)
    float* feat  = (float*)(idxlist + (size_t)MM * MAXK); // M * FEAT floats (6.8 MB)

    hipMemsetAsync(cnt, 0, MM * sizeof(int), stream);

    int total4 = NN * MM / 4;                           // 8,388,608 float4s
    build_csc<<<total4 / 256, 256, 0, stream>>>(H, cnt, idxlist);
    stats_kernel<<<MM, DD, 0, stream>>>(x, cnt, idxlist, feat, t, Wt, bt);
    mlp_kernel<<<MM / 4, 256, 0, stream>>>(feat, W1, b1, W2, b2, W3, b3, out);
}

// Round 2
// 86.123 us; speedup vs baseline: 1.3783x; 1.3783x over previous
//
#include <hip/hip_runtime.h>
#include <math.h>

#define NN 8192
#define MM 4096
#define DD 128
#define TDIM 32
#define H1DIM 64
#define H2DIM 32
#define FEAT (3*DD + TDIM)   // 416
#define KGROUPS (FEAT/4)     // 104
#define MAXK 256
#define BIGF 1e30f

// Pass 1: compress dense incidence H (N x M, row-major) into per-column index
// lists. Coalesced float4 read of H; atomic append of row index n per nonzero.
__global__ void build_csc(const float* __restrict__ H,
                          int* __restrict__ cnt, int* __restrict__ idxlist) {
    int tid = blockIdx.x * blockDim.x + threadIdx.x;   // one float4 per thread
    const float4* H4 = reinterpret_cast<const float4*>(H);
    float4 v = H4[tid];
    int base = tid * 4;              // flat index into H
    int n = base >> 12;              // row (node)   (MM = 4096)
    int m = base & (MM - 1);         // col (hyperedge); MM % 4 == 0 so all 4 same row
    float vals[4] = {v.x, v.y, v.z, v.w};
    #pragma unroll
    for (int i = 0; i < 4; ++i) {
        if (vals[i] != 0.0f) {
            int p = atomicAdd(&cnt[m + i], 1);
            if (p < MAXK) idxlist[(m + i) * MAXK + p] = n;
        }
    }
}

// Pack weights for coalesced reads in the MLP:
//   W1P (as float4): W1P4[g*64 + j] = {W1[j][4g+0..3]}   (g < 104, j < 64)
//   W2T:             W2T[k*32 + j2] = W2[j2][k]          (k < 64, j2 < 32)
__global__ void pack_weights(const float* __restrict__ W1, const float* __restrict__ W2,
                             float* __restrict__ W1P, float* __restrict__ W2T) {
    int tid = blockIdx.x * blockDim.x + threadIdx.x;
    if (tid < FEAT * H1DIM) {
        int c = tid & 3, j = (tid >> 2) & 63, g = tid >> 8;
        W1P[tid] = W1[j * FEAT + g * 4 + c];
    } else {
        int t2 = tid - FEAT * H1DIM;       // < 2048
        int k = t2 >> 5, j2 = t2 & 31;
        W2T[t2] = W2[j2 * H1DIM + k];
    }
}

// Pass 2: per-hyperedge stats. Block = one hyperedge (M blocks), thread = dim d.
__global__ void stats_kernel(const float* __restrict__ x,
                             const int* __restrict__ cnt,
                             const int* __restrict__ idxlist,
                             float* __restrict__ feat,
                             const float* __restrict__ tptr,
                             const float* __restrict__ Wt,
                             const float* __restrict__ bt) {
    int m = blockIdx.x;
    int d = threadIdx.x;
    int K = cnt[m]; if (K > MAXK) K = MAXK;
    const int* lst = idxlist + m * MAXK;
    float s = 0.f, s2 = 0.f, mx = -BIGF, mn = BIGF;
    for (int i = 0; i < K; ++i) {
        int n = lst[i];                  // same addr across block (broadcast)
        float v = x[n * DD + d];         // coalesced 512B across block
        s  += v;
        s2 += v * v;
        mx = fmaxf(mx, v);
        mn = fminf(mn, v);
    }
    float deg = (K > 0) ? (float)K : 1.0f;   // clip(sum H, 1.0)
    float mu  = s / deg;
    float var = s2 / deg - mu * mu;
    float sg  = sqrtf(fmaxf(var, 1e-8f));
    float dl  = (K > 0) ? (mx - mn) : 0.0f;
    float* f = feat + m * FEAT;
    f[d]        = mu;
    f[DD + d]   = sg;
    f[2*DD + d] = dl;
    if (d < TDIM) {
        float te = tptr[0] * Wt[d] + bt[d];  // W_t is (TDIM,1)
        f[3*DD + d] = fmaxf(te, 0.0f);
    }
}

// Pass 3: MLP 416 -> 64 -> 32 -> 1 (sigmoid).
// Block = 256 threads = 4 waves; each wave handles 4 rows (16 rows/block).
// Layer 1: lane = output unit j; W1P gives one coalesced float4 load per
// k-group serving 4 rows (16 FMA per 1KB wave-load).
__global__ __launch_bounds__(256) void mlp_kernel(
        const float* __restrict__ feat,
        const float* __restrict__ W1P, const float* __restrict__ b1,
        const float* __restrict__ W2T, const float* __restrict__ b2,
        const float* __restrict__ W3, const float* __restrict__ b3,
        float* __restrict__ out) {
    int t = threadIdx.x;
    int wave = t >> 6, lane = t & 63;
    int rbase = blockIdx.x * 16 + wave * 4;

    const float4* W1P4 = reinterpret_cast<const float4*>(W1P);
    const float4* f0 = reinterpret_cast<const float4*>(feat + (rbase + 0) * FEAT);
    const float4* f1 = reinterpret_cast<const float4*>(feat + (rbase + 1) * FEAT);
    const float4* f2 = reinterpret_cast<const float4*>(feat + (rbase + 2) * FEAT);
    const float4* f3 = reinterpret_cast<const float4*>(feat + (rbase + 3) * FEAT);

    float bb = b1[lane];
    float acc0 = bb, acc1 = bb, acc2 = bb, acc3 = bb;
    #pragma unroll 4
    for (int g = 0; g < KGROUPS; ++g) {
        float4 w = W1P4[g * H1DIM + lane];       // coalesced, L1/L2-resident
        float4 a0 = f0[g];                        // uniform (broadcast) loads
        float4 a1 = f1[g];
        float4 a2 = f2[g];
        float4 a3 = f3[g];
        acc0 += a0.x*w.x + a0.y*w.y + a0.z*w.z + a0.w*w.w;
        acc1 += a1.x*w.x + a1.y*w.y + a1.z*w.z + a1.w*w.w;
        acc2 += a2.x*w.x + a2.y*w.y + a2.z*w.z + a2.w*w.w;
        acc3 += a3.x*w.x + a3.y*w.y + a3.z*w.z + a3.w*w.w;
    }

    __shared__ float hs1[16][H1DIM];
    hs1[wave*4 + 0][lane] = fmaxf(acc0, 0.f);
    hs1[wave*4 + 1][lane] = fmaxf(acc1, 0.f);
    hs1[wave*4 + 2][lane] = fmaxf(acc2, 0.f);
    hs1[wave*4 + 3][lane] = fmaxf(acc3, 0.f);
    __syncthreads();

    // Layers 2+3, per wave over its 4 rows. j2 = lane&31, k split by half-wave.
    int j2 = lane & 31;
    int kh = (lane >> 5) * 32;
    float w3v = W3[j2];
    float b2v = b2[j2];
    #pragma unroll
    for (int r = 0; r < 4; ++r) {
        int row = wave * 4 + r;
        float a2 = 0.f;
        #pragma unroll
        for (int kk = 0; kk < 32; ++kk) {
            int k = kh + kk;
            a2 += hs1[row][k] * W2T[k * H2DIM + j2];   // hs1: broadcast; W2T: coalesced
        }
        a2 += __shfl_xor(a2, 32);                      // combine k-halves
        float h2 = fmaxf(a2 + b2v, 0.f);
        float p = h2 * w3v;
        p += __shfl_xor(p, 16);
        p += __shfl_xor(p, 8);
        p += __shfl_xor(p, 4);
        p += __shfl_xor(p, 2);
        p += __shfl_xor(p, 1);
        if (lane == 0) out[rbase + r] = 1.f / (1.f + expf(-(p + b3[0])));
    }
}

extern "C" void kernel_launch(void* const* d_in, const int* in_sizes, int n_in,
                              void* d_out, int out_size, void* d_ws, size_t ws_size,
                              hipStream_t stream) {
    const float* x   = (const float*)d_in[0];   // (N, D)
    const float* H   = (const float*)d_in[1];   // (N, M)
    const float* t   = (const float*)d_in[2];   // (1,)
    const float* Wt  = (const float*)d_in[3];   // (TDIM, 1)
    const float* bt  = (const float*)d_in[4];   // (TDIM,)
    const float* W1  = (const float*)d_in[5];   // (64, 416)
    const float* b1  = (const float*)d_in[6];
    const float* W2  = (const float*)d_in[7];   // (32, 64)
    const float* b2  = (const float*)d_in[8];
    const float* W3  = (const float*)d_in[9];   // (1, 32)
    const float* b3  = (const float*)d_in[10];
    float* out = (float*)d_out;

    // workspace layout
    int* cnt     = (int*)d_ws;                            // M ints (16 KB)
    int* idxlist = cnt + MM;                              // M*MAXK ints (4 MB)
    float* feat  = (float*)(idxlist + (size_t)MM * MAXK); // M*FEAT floats (6.8 MB)
    float* W1P   = feat + (size_t)MM * FEAT;              // 26624 floats
    float* W2T   = W1P + FEAT * H1DIM;                    // 2048 floats

    hipMemsetAsync(cnt, 0, MM * sizeof(int), stream);
    pack_weights<<<(FEAT*H1DIM + H1DIM*H2DIM) / 256, 256, 0, stream>>>(W1, W2, W1P, W2T);

    int total4 = NN * MM / 4;                             // 8,388,608 float4s
    build_csc<<<total4 / 256, 256, 0, stream>>>(H, cnt, idxlist);
    stats_kernel<<<MM, DD, 0, stream>>>(x, cnt, idxlist, feat, t, Wt, bt);
    mlp_kernel<<<MM / 16, 256, 0, stream>>>(feat, W1P, b1, W2T, b2, W3, b3, out);
}

// Round 4
// 75.940 us; speedup vs baseline: 1.5631x; 1.1341x over previous
//
#include <hip/hip_runtime.h>
#include <math.h>

#define NN 8192
#define MM 4096
#define DD 128
#define TDIM 32
#define H1DIM 64
#define H2DIM 32
#define FEAT (3*DD + TDIM)   // 416
#define KGROUPS (FEAT/4)     // 104
#define MAXK 256
#define BIGF 1e30f
#define CSC_ILP 4

typedef float fvec4 __attribute__((ext_vector_type(4)));   // builtin-compatible

// Prep: pack W1 into lane-coalesced layout, transpose W2, zero cnt.
//   W1P (as float4): W1P4[g*64 + j] = {W1[j][4g+0..3]}   (g < 104, j < 64)
//   W2T:             W2T[k*32 + j2] = W2[j2][k]          (k < 64, j2 < 32)
__global__ void prep_kernel(const float* __restrict__ W1, const float* __restrict__ W2,
                            float* __restrict__ W1P, float* __restrict__ W2T,
                            int* __restrict__ cnt) {
    int tid = blockIdx.x * blockDim.x + threadIdx.x;
    if (tid < FEAT * H1DIM) {                       // 26624
        int c = tid & 3, j = (tid >> 2) & 63, g = tid >> 8;
        W1P[tid] = W1[j * FEAT + g * 4 + c];
    } else if (tid < FEAT * H1DIM + H1DIM * H2DIM) { // +2048
        int t2 = tid - FEAT * H1DIM;
        W2T[t2] = W2[(t2 & 31) * H1DIM + (t2 >> 5)];
    } else if (tid < FEAT * H1DIM + H1DIM * H2DIM + MM) {
        cnt[tid - FEAT * H1DIM - H1DIM * H2DIM] = 0;
    }
}

// Pass 1: dense H (N x M, row-major) -> per-column (hyperedge) index lists.
// 4 float4s per thread for deep MLP (memory-level parallelism), nontemporal
// (read-once) loads, all-zero fast path per float4.
__global__ void build_csc(const float* __restrict__ H,
                          int* __restrict__ cnt, int* __restrict__ idxlist) {
    const fvec4* H4 = reinterpret_cast<const fvec4*>(H);
    int t0 = blockIdx.x * (256 * CSC_ILP) + threadIdx.x;
    #pragma unroll
    for (int k = 0; k < CSC_ILP; ++k) {
        int idx4 = t0 + k * 256;
        fvec4 v = __builtin_nontemporal_load(&H4[idx4]);
        if (v.x != 0.f || v.y != 0.f || v.z != 0.f || v.w != 0.f) {
            int base = idx4 * 4;
            int n = base >> 12;              // row (node), MM = 4096
            int mcol = base & (MM - 1);      // col (hyperedge)
            float vals[4] = {v.x, v.y, v.z, v.w};
            #pragma unroll
            for (int i = 0; i < 4; ++i) {
                if (vals[i] != 0.0f) {
                    int p = atomicAdd(&cnt[mcol + i], 1);
                    if (p < MAXK) idxlist[(mcol + i) * MAXK + p] = n;
                }
            }
        }
    }
}

// Pass 2: per-hyperedge stats. Block = one hyperedge, thread = dim d.
// int4 index prefetch + 4 independent x-gathers in flight per iteration.
__global__ void stats_kernel(const float* __restrict__ x,
                             const int* __restrict__ cnt,
                             const int* __restrict__ idxlist,
                             float* __restrict__ feat,
                             const float* __restrict__ tptr,
                             const float* __restrict__ Wt,
                             const float* __restrict__ bt) {
    int m = blockIdx.x;
    int d = threadIdx.x;
    int K = cnt[m]; if (K > MAXK) K = MAXK;
    const int* lst = idxlist + m * MAXK;     // 1KB-aligned rows
    float s = 0.f, s2 = 0.f, mx = -BIGF, mn = BIGF;
    int i = 0;
    for (; i + 4 <= K; i += 4) {
        int4 nn = *reinterpret_cast<const int4*>(lst + i);
        float v0 = x[nn.x * DD + d];
        float v1 = x[nn.y * DD + d];
        float v2 = x[nn.z * DD + d];
        float v3 = x[nn.w * DD + d];
        s  += (v0 + v1) + (v2 + v3);
        s2 += (v0*v0 + v1*v1) + (v2*v2 + v3*v3);
        mx = fmaxf(mx, fmaxf(fmaxf(v0, v1), fmaxf(v2, v3)));
        mn = fminf(mn, fminf(fminf(v0, v1), fminf(v2, v3)));
    }
    for (; i < K; ++i) {
        int n = lst[i];
        float v = x[n * DD + d];
        s += v; s2 += v * v;
        mx = fmaxf(mx, v); mn = fminf(mn, v);
    }
    float deg = (K > 0) ? (float)K : 1.0f;   // clip(sum H, 1.0)
    float mu  = s / deg;
    float var = s2 / deg - mu * mu;
    float sg  = sqrtf(fmaxf(var, 1e-8f));
    float dl  = (K > 0) ? (mx - mn) : 0.0f;
    float* f = feat + m * FEAT;
    f[d]        = mu;
    f[DD + d]   = sg;
    f[2*DD + d] = dl;
    if (d < TDIM) {
        float te = tptr[0] * Wt[d] + bt[d];  // W_t is (TDIM,1)
        f[3*DD + d] = fmaxf(te, 0.0f);
    }
}

// Pass 3: MLP 416 -> 64 -> 32 -> 1 (sigmoid). 4 waves/block, 4 rows/wave.
__global__ __launch_bounds__(256) void mlp_kernel(
        const float* __restrict__ feat,
        const float* __restrict__ W1P, const float* __restrict__ b1,
        const float* __restrict__ W2T, const float* __restrict__ b2,
        const float* __restrict__ W3, const float* __restrict__ b3,
        float* __restrict__ out) {
    int t = threadIdx.x;
    int wave = t >> 6, lane = t & 63;
    int rbase = blockIdx.x * 16 + wave * 4;

    const float4* W1P4 = reinterpret_cast<const float4*>(W1P);
    const float4* f0 = reinterpret_cast<const float4*>(feat + (rbase + 0) * FEAT);
    const float4* f1 = reinterpret_cast<const float4*>(feat + (rbase + 1) * FEAT);
    const float4* f2 = reinterpret_cast<const float4*>(feat + (rbase + 2) * FEAT);
    const float4* f3 = reinterpret_cast<const float4*>(feat + (rbase + 3) * FEAT);

    float bb = b1[lane];
    float acc0 = bb, acc1 = bb, acc2 = bb, acc3 = bb;
    #pragma unroll 4
    for (int g = 0; g < KGROUPS; ++g) {
        float4 w = W1P4[g * H1DIM + lane];       // coalesced, L1/L2-resident
        float4 a0 = f0[g];                        // uniform (broadcast) loads
        float4 a1 = f1[g];
        float4 a2 = f2[g];
        float4 a3 = f3[g];
        acc0 += a0.x*w.x + a0.y*w.y + a0.z*w.z + a0.w*w.w;
        acc1 += a1.x*w.x + a1.y*w.y + a1.z*w.z + a1.w*w.w;
        acc2 += a2.x*w.x + a2.y*w.y + a2.z*w.z + a2.w*w.w;
        acc3 += a3.x*w.x + a3.y*w.y + a3.z*w.z + a3.w*w.w;
    }

    __shared__ float hs1[16][H1DIM];
    hs1[wave*4 + 0][lane] = fmaxf(acc0, 0.f);
    hs1[wave*4 + 1][lane] = fmaxf(acc1, 0.f);
    hs1[wave*4 + 2][lane] = fmaxf(acc2, 0.f);
    hs1[wave*4 + 3][lane] = fmaxf(acc3, 0.f);
    __syncthreads();

    int j2 = lane & 31;
    int kh = (lane >> 5) * 32;
    float w3v = W3[j2];
    float b2v = b2[j2];
    #pragma unroll
    for (int r = 0; r < 4; ++r) {
        int row = wave * 4 + r;
        float a2 = 0.f;
        #pragma unroll
        for (int kk = 0; kk < 32; ++kk) {
            int k = kh + kk;
            a2 += hs1[row][k] * W2T[k * H2DIM + j2];   // hs1: broadcast; W2T: coalesced
        }
        a2 += __shfl_xor(a2, 32);                      // combine k-halves
        float h2 = fmaxf(a2 + b2v, 0.f);
        float p = h2 * w3v;
        p += __shfl_xor(p, 16);
        p += __shfl_xor(p, 8);
        p += __shfl_xor(p, 4);
        p += __shfl_xor(p, 2);
        p += __shfl_xor(p, 1);
        if (lane == 0) out[rbase + r] = 1.f / (1.f + expf(-(p + b3[0])));
    }
}

extern "C" void kernel_launch(void* const* d_in, const int* in_sizes, int n_in,
                              void* d_out, int out_size, void* d_ws, size_t ws_size,
                              hipStream_t stream) {
    const float* x   = (const float*)d_in[0];   // (N, D)
    const float* H   = (const float*)d_in[1];   // (N, M)
    const float* t   = (const float*)d_in[2];   // (1,)
    const float* Wt  = (const float*)d_in[3];   // (TDIM, 1)
    const float* bt  = (const float*)d_in[4];   // (TDIM,)
    const float* W1  = (const float*)d_in[5];   // (64, 416)
    const float* b1  = (const float*)d_in[6];
    const float* W2  = (const float*)d_in[7];   // (32, 64)
    const float* b2  = (const float*)d_in[8];
    const float* W3  = (const float*)d_in[9];   // (1, 32)
    const float* b3  = (const float*)d_in[10];
    float* out = (float*)d_out;

    // workspace layout
    int* cnt     = (int*)d_ws;                            // M ints (16 KB)
    int* idxlist = cnt + MM;                              // M*MAXK ints (4 MB)
    float* feat  = (float*)(idxlist + (size_t)MM * MAXK); // M*FEAT floats (6.8 MB)
    float* W1P   = feat + (size_t)MM * FEAT;              // 26624 floats
    float* W2T   = W1P + FEAT * H1DIM;                    // 2048 floats

    int prep_n = FEAT*H1DIM + H1DIM*H2DIM + MM;           // 32768
    prep_kernel<<<(prep_n + 255) / 256, 256, 0, stream>>>(W1, W2, W1P, W2T, cnt);

    int total4 = NN * MM / 4;                             // 8,388,608 float4s
    build_csc<<<total4 / (256 * CSC_ILP), 256, 0, stream>>>(H, cnt, idxlist);
    stats_kernel<<<MM, DD, 0, stream>>>(x, cnt, idxlist, feat, t, Wt, bt);
    mlp_kernel<<<MM / 16, 256, 0, stream>>>(feat, W1P, b1, W2T, b2, W3, b3, out);
}